// Round 1
// baseline (76.445 us; speedup 1.0000x reference)
//
#include <hip/hip_runtime.h>

// DWT 2D Haar, fused depthwise stride-2 2x2 conv -> 4 subbands.
// x: [8, 96, 256, 256] f32; filters: 4 x [1,1,2,2] f32
// out: [8, 4*96, 128, 128] f32, channel = k*96 + c, k in {ll, lh, hl, hh}

#define B_ 8
#define C_ 96
#define H_ 256
#define W_ 256
#define HO_ (H_ / 2)
#define WO_ (W_ / 2)
#define W8_ (W_ / 8)   // 8-input-col groups per row = 4 output cols

__device__ __forceinline__ float4 apply_filter(float4 f,
                                               float a0, float b0, float c0, float d0,
                                               float a1, float b1, float c1, float d1,
                                               float a2, float b2, float c2, float d2,
                                               float a3, float b3, float c3, float d3) {
    float4 o;
    o.x = f.x * a0 + f.y * b0 + f.z * c0 + f.w * d0;
    o.y = f.x * a1 + f.y * b1 + f.z * c1 + f.w * d1;
    o.z = f.x * a2 + f.y * b2 + f.z * c2 + f.w * d2;
    o.w = f.x * a3 + f.y * b3 + f.z * c3 + f.w * d3;
    return o;
}

__global__ __launch_bounds__(256) void dwt_haar_kernel(
    const float* __restrict__ x,
    const float* __restrict__ wll,
    const float* __restrict__ wlh,
    const float* __restrict__ whl,
    const float* __restrict__ whh,
    float* __restrict__ out)
{
    const int total = B_ * C_ * HO_ * W8_;   // 3,145,728
    int idx = blockIdx.x * blockDim.x + threadIdx.x;
    if (idx >= total) return;

    const int w8 = idx % W8_;
    const int h  = (idx / W8_) % HO_;
    const int bc = idx / (W8_ * HO_);        // b*C + c
    const int b  = bc / C_;
    const int c  = bc % C_;

    // filter taps: f[i][j] flattened row-major -> (f.x,f.y) row i=0, (f.z,f.w) row i=1
    const float4 f_ll = *reinterpret_cast<const float4*>(wll);
    const float4 f_lh = *reinterpret_cast<const float4*>(wlh);
    const float4 f_hl = *reinterpret_cast<const float4*>(whl);
    const float4 f_hh = *reinterpret_cast<const float4*>(whh);

    // input rows 2h and 2h+1, cols [8*w8, 8*w8+8)
    const float* row0 = x + ((size_t)bc * H_ + 2 * h) * W_ + w8 * 8;
    const float* row1 = row0 + W_;
    const float4 r0a = reinterpret_cast<const float4*>(row0)[0];
    const float4 r0b = reinterpret_cast<const float4*>(row0)[1];
    const float4 r1a = reinterpret_cast<const float4*>(row1)[0];
    const float4 r1b = reinterpret_cast<const float4*>(row1)[1];

    // per output col p: a = x[2h, 2w], b = x[2h, 2w+1], c = x[2h+1, 2w], d = x[2h+1, 2w+1]
    // col 0: r0a.x r0a.y r1a.x r1a.y
    // col 1: r0a.z r0a.w r1a.z r1a.w
    // col 2: r0b.x r0b.y r1b.x r1b.y
    // col 3: r0b.z r0b.w r1b.z r1b.w
    float4 o_ll = apply_filter(f_ll, r0a.x, r0a.y, r1a.x, r1a.y,
                                     r0a.z, r0a.w, r1a.z, r1a.w,
                                     r0b.x, r0b.y, r1b.x, r1b.y,
                                     r0b.z, r0b.w, r1b.z, r1b.w);
    float4 o_lh = apply_filter(f_lh, r0a.x, r0a.y, r1a.x, r1a.y,
                                     r0a.z, r0a.w, r1a.z, r1a.w,
                                     r0b.x, r0b.y, r1b.x, r1b.y,
                                     r0b.z, r0b.w, r1b.z, r1b.w);
    float4 o_hl = apply_filter(f_hl, r0a.x, r0a.y, r1a.x, r1a.y,
                                     r0a.z, r0a.w, r1a.z, r1a.w,
                                     r0b.x, r0b.y, r1b.x, r1b.y,
                                     r0b.z, r0b.w, r1b.z, r1b.w);
    float4 o_hh = apply_filter(f_hh, r0a.x, r0a.y, r1a.x, r1a.y,
                                     r0a.z, r0a.w, r1a.z, r1a.w,
                                     r0b.x, r0b.y, r1b.x, r1b.y,
                                     r0b.z, r0b.w, r1b.z, r1b.w);

    // out[b, k*C + c, h, 4*w8 .. 4*w8+3]
    const size_t plane = (size_t)HO_ * WO_;
    float* obase = out + (((size_t)b * 4 * C_ + c) * HO_ + h) * WO_ + w8 * 4;
    reinterpret_cast<float4*>(obase + 0 * C_ * plane)[0] = o_ll;
    reinterpret_cast<float4*>(obase + 1 * C_ * plane)[0] = o_lh;
    reinterpret_cast<float4*>(obase + 2 * C_ * plane)[0] = o_hl;
    reinterpret_cast<float4*>(obase + 3 * C_ * plane)[0] = o_hh;
}

extern "C" void kernel_launch(void* const* d_in, const int* in_sizes, int n_in,
                              void* d_out, int out_size, void* d_ws, size_t ws_size,
                              hipStream_t stream) {
    const float* x   = (const float*)d_in[0];
    const float* wll = (const float*)d_in[1];
    const float* wlh = (const float*)d_in[2];
    const float* whl = (const float*)d_in[3];
    const float* whh = (const float*)d_in[4];
    float* out = (float*)d_out;

    const int total = B_ * C_ * HO_ * W8_;
    const int block = 256;
    const int grid = (total + block - 1) / block;   // 12288 blocks
    dwt_haar_kernel<<<grid, block, 0, stream>>>(x, wll, wlh, whl, whh, out);
}

// Round 2
// 62.619 us; speedup vs baseline: 1.2208x; 1.2208x over previous
//
#include <hip/hip_runtime.h>

// DWT 2D Haar, fused depthwise stride-2 2x2 conv -> 4 subbands.
// x: [8, 96, 256, 256] f32; filters: 4 x [1,1,2,2] f32
// out: [8, 4*96, 128, 128] f32, channel = k*96 + c, k in {ll, lh, hl, hh}
//
// R2: non-temporal output stores. Output (201 MB) streams past L2/L3 so the
// input (201 MB < 256 MB Infinity Cache) can stay L3-resident across graph
// replays -> read path served from L3, HBM sees mostly the write stream.

#define B_ 8
#define C_ 96
#define H_ 256
#define W_ 256
#define HO_ (H_ / 2)
#define WO_ (W_ / 2)
#define W8_ (W_ / 8)   // 8-input-col groups per row = 4 output cols

__device__ __forceinline__ float4 apply_filter(float4 f,
                                               float a0, float b0, float c0, float d0,
                                               float a1, float b1, float c1, float d1,
                                               float a2, float b2, float c2, float d2,
                                               float a3, float b3, float c3, float d3) {
    float4 o;
    o.x = f.x * a0 + f.y * b0 + f.z * c0 + f.w * d0;
    o.y = f.x * a1 + f.y * b1 + f.z * c1 + f.w * d1;
    o.z = f.x * a2 + f.y * b2 + f.z * c2 + f.w * d2;
    o.w = f.x * a3 + f.y * b3 + f.z * c3 + f.w * d3;
    return o;
}

__device__ __forceinline__ void nt_store4(float* p, float4 v) {
    __builtin_nontemporal_store(v.x, p + 0);
    __builtin_nontemporal_store(v.y, p + 1);
    __builtin_nontemporal_store(v.z, p + 2);
    __builtin_nontemporal_store(v.w, p + 3);
}

__global__ __launch_bounds__(256) void dwt_haar_kernel(
    const float* __restrict__ x,
    const float* __restrict__ wll,
    const float* __restrict__ wlh,
    const float* __restrict__ whl,
    const float* __restrict__ whh,
    float* __restrict__ out)
{
    const int total = B_ * C_ * HO_ * W8_;   // 3,145,728
    int idx = blockIdx.x * blockDim.x + threadIdx.x;
    if (idx >= total) return;

    const int w8 = idx % W8_;
    const int h  = (idx / W8_) % HO_;
    const int bc = idx / (W8_ * HO_);        // b*C + c
    const int b  = bc / C_;
    const int c  = bc % C_;

    // filter taps: f[i][j] flattened row-major -> (f.x,f.y) row i=0, (f.z,f.w) row i=1
    const float4 f_ll = *reinterpret_cast<const float4*>(wll);
    const float4 f_lh = *reinterpret_cast<const float4*>(wlh);
    const float4 f_hl = *reinterpret_cast<const float4*>(whl);
    const float4 f_hh = *reinterpret_cast<const float4*>(whh);

    // input rows 2h and 2h+1, cols [8*w8, 8*w8+8)
    const float* row0 = x + ((size_t)bc * H_ + 2 * h) * W_ + w8 * 8;
    const float* row1 = row0 + W_;
    const float4 r0a = reinterpret_cast<const float4*>(row0)[0];
    const float4 r0b = reinterpret_cast<const float4*>(row0)[1];
    const float4 r1a = reinterpret_cast<const float4*>(row1)[0];
    const float4 r1b = reinterpret_cast<const float4*>(row1)[1];

    // per output col p: a = x[2h, 2w], b = x[2h, 2w+1], c = x[2h+1, 2w], d = x[2h+1, 2w+1]
    float4 o_ll = apply_filter(f_ll, r0a.x, r0a.y, r1a.x, r1a.y,
                                     r0a.z, r0a.w, r1a.z, r1a.w,
                                     r0b.x, r0b.y, r1b.x, r1b.y,
                                     r0b.z, r0b.w, r1b.z, r1b.w);
    float4 o_lh = apply_filter(f_lh, r0a.x, r0a.y, r1a.x, r1a.y,
                                     r0a.z, r0a.w, r1a.z, r1a.w,
                                     r0b.x, r0b.y, r1b.x, r1b.y,
                                     r0b.z, r0b.w, r1b.z, r1b.w);
    float4 o_hl = apply_filter(f_hl, r0a.x, r0a.y, r1a.x, r1a.y,
                                     r0a.z, r0a.w, r1a.z, r1a.w,
                                     r0b.x, r0b.y, r1b.x, r1b.y,
                                     r0b.z, r0b.w, r1b.z, r1b.w);
    float4 o_hh = apply_filter(f_hh, r0a.x, r0a.y, r1a.x, r1a.y,
                                     r0a.z, r0a.w, r1a.z, r1a.w,
                                     r0b.x, r0b.y, r1b.x, r1b.y,
                                     r0b.z, r0b.w, r1b.z, r1b.w);

    // out[b, k*C + c, h, 4*w8 .. 4*w8+3]
    const size_t plane = (size_t)HO_ * WO_;
    float* obase = out + (((size_t)b * 4 * C_ + c) * HO_ + h) * WO_ + w8 * 4;
    nt_store4(obase + 0 * C_ * plane, o_ll);
    nt_store4(obase + 1 * C_ * plane, o_lh);
    nt_store4(obase + 2 * C_ * plane, o_hl);
    nt_store4(obase + 3 * C_ * plane, o_hh);
}

extern "C" void kernel_launch(void* const* d_in, const int* in_sizes, int n_in,
                              void* d_out, int out_size, void* d_ws, size_t ws_size,
                              hipStream_t stream) {
    const float* x   = (const float*)d_in[0];
    const float* wll = (const float*)d_in[1];
    const float* wlh = (const float*)d_in[2];
    const float* whl = (const float*)d_in[3];
    const float* whh = (const float*)d_in[4];
    float* out = (float*)d_out;

    const int total = B_ * C_ * HO_ * W8_;
    const int block = 256;
    const int grid = (total + block - 1) / block;   // 12288 blocks
    dwt_haar_kernel<<<grid, block, 0, stream>>>(x, wll, wlh, whl, whh, out);
}